// Round 14
// baseline (314.176 us; speedup 1.0000x reference)
//
#include <hip/hip_runtime.h>
#include <math.h>
#include <float.h>

#define PH 7
#define RLEN 32   // ints per roi in workspace

// ---- exact integer emulation of the reference's fast-math f32 binning ----
// bin = RN_f32(roi * RN_f32(1/7));  RN_f32(1/7) = 9586981 * 2^-26
#define C7 9586981LL

__device__ __forceinline__ long long round24(long long v) {
    if (v == 0) return 0;
    int L = 64 - __clzll((unsigned long long)v);
    int sh = L - 24;
    if (sh <= 0) return v;
    long long rem  = v & ((1LL << sh) - 1);
    long long base = v >> sh;
    long long half = 1LL << (sh - 1);
    if (rem > half || (rem == half && (base & 1))) base++;
    return base << sh;
}
__device__ __forceinline__ long long bin_q26(int roi) {
    return round24((long long)roi * C7);
}
__device__ __forceinline__ int floor_k(long long b26, int k) {
    long long v = round24((long long)k * b26);
    return (int)(v >> 26);
}
__device__ __forceinline__ int ceil_k(long long b26, int k) {
    long long v = round24((long long)k * b26);
    return (int)((v + ((1LL << 26) - 1)) >> 26);
}

// Per-ROI bounds (ints): [0]=b, [1..7]=hstart, [8..14]=hend,
// [15] = qs | qe<<8 (window column-quad range), [16..22]=ws, [23..29]=we
__global__ void roi_bounds_kernel(const float* __restrict__ rois,
                                  int* __restrict__ wsbuf, int R) {
    int r = blockIdx.x * blockDim.x + threadIdx.x;
    if (r >= R) return;
    const int H = 64, W = 64;
    const float* roi = rois + r * 5;
    int b  = (int)roi[0];
    int x1 = (int)rintf(roi[1] * 0.0625f);
    int y1 = (int)rintf(roi[2] * 0.0625f);
    int x2 = (int)rintf(roi[3] * 0.0625f);
    int y2 = (int)rintf(roi[4] * 0.0625f);

    int roi_w = max(x2 - x1 + 1, 1);
    int roi_h = max(y2 - y1 + 1, 1);
    long long bh = bin_q26(roi_h);
    long long bw = bin_q26(roi_w);

    int* o = wsbuf + r * RLEN;
    o[0] = b;
    int ws0 = 64, we6 = 0;
    #pragma unroll
    for (int i = 0; i < PH; ++i) {
        int hs = min(max(y1 + floor_k(bh, i),     0), H);
        int he = min(max(y1 + ceil_k (bh, i + 1), 0), H);
        int wst = min(max(x1 + floor_k(bw, i),     0), W);
        int wen = min(max(x1 + ceil_k (bw, i + 1), 0), W);
        o[1 + i]  = hs;
        o[8 + i]  = he;
        o[16 + i] = wst;
        o[23 + i] = wen;
        if (i == 0) ws0 = wst;
        if (i == 6) we6 = wen;
    }
    int qs = ws0 >> 2;
    int qe = (we6 + 3) >> 2;
    o[15] = qs | (max(qe, qs) << 8);
}

__device__ __forceinline__ float4 max4(float4 a, float4 b) {
    float4 r;
    r.x = fmaxf(a.x, b.x); r.y = fmaxf(a.y, b.y);
    r.z = fmaxf(a.z, b.z); r.w = fmaxf(a.w, b.w);
    return r;
}

// One wave = 16 channels of one roi. lane = chsub*4 + cq4; quad = qs+t*4+cq4.
// 4-quad tiles track the window tightly (avg lane util ~75%).
// Per-phase reduce (2 rounds of 8ch x 7pw) into registers; one coalesced
// 784-float write at the end staged through the wave's LDS slice. No barriers.
// Block = 256 threads = 4 independent waves. Grid = R * 8.
__global__ __launch_bounds__(256) void roipool_main(
        const float* __restrict__ features,
        const int* __restrict__ wsbuf,
        float* __restrict__ out) {
    __shared__ float cm[4][16][68];  // [wave][chsub][cols] = 17408 B

    int r    = blockIdx.x >> 3;      // 8 blocks per roi (64 ch each)
    int cg   = blockIdx.x & 7;
    int wv   = threadIdx.x >> 6;
    int lane = threadIdx.x & 63;
    int chsub = lane >> 2;           // 0..15: channel within wave
    int cq4   = lane & 3;            // quad slot within tile
    int c0   = (cg << 6) + (wv << 4);

    const int* B = wsbuf + r * RLEN; // wave-uniform -> scalar loads
    int b   = B[0];
    int qpk = B[15];
    int qs  = qpk & 255;
    int qe  = qpk >> 8;
    int ntiles = (qe - qs + 3) >> 2; // 0..4

    const float4* f4 = (const float4*)features;
    int cbase = ((b << 9) + c0 + chsub) << 10;

    // epilogue lane mapping: 2 rounds of 8 ch * 7 pw = 56 active lanes
    int ech = (lane * 9363) >> 16;   // lane/7 for lane<56
    int epw = lane - ech * 7;
    int ews = B[16 + epw];           // per-lane, L1-hot
    int ewe = B[23 + epw];
    bool eact = lane < 56;
    const float* erow0 = cm[wv][ech & 7];
    const float* erow1 = cm[wv][8 + (ech & 7)];
    float vals0[PH], vals1[PH];

    #pragma unroll
    for (int ph = 0; ph < PH; ++ph) {
        int hs = B[1 + ph], he = B[8 + ph];   // wave-uniform scalars
        for (int t = 0; t < ntiles; ++t) {
            int qabs = qs + (t << 2) + cq4;
            if (qabs < qe) {
                float4 acc = make_float4(-FLT_MAX, -FLT_MAX, -FLT_MAX, -FLT_MAX);
                int n = he - hs;
                int idx = cbase + (hs << 4) + qabs;
                while (n >= 4) {                  // 4 loads in flight
                    float4 v0 = f4[idx];
                    float4 v1 = f4[idx + 16];
                    float4 v2 = f4[idx + 32];
                    float4 v3 = f4[idx + 48];
                    acc = max4(acc, max4(max4(v0, v1), max4(v2, v3)));
                    idx += 64; n -= 4;
                }
                if (n >= 2) {
                    float4 v0 = f4[idx];
                    float4 v1 = f4[idx + 16];
                    acc = max4(acc, max4(v0, v1));
                    idx += 32; n -= 2;
                }
                if (n > 0) acc = max4(acc, f4[idx]);
                *(float4*)&cm[wv][chsub][qabs << 2] = acc;
            }
        }
        // per-phase reduce into registers; wave-lockstep order makes this safe
        bool empty = (he <= hs) || (ewe <= ews);
        {
            float m = -FLT_MAX;
            int w = ews;
            for (; w + 2 <= ewe; w += 2)
                m = fmaxf(fmaxf(m, erow0[w]), erow0[w + 1]);
            if (w < ewe) m = fmaxf(m, erow0[w]);
            vals0[ph] = empty ? 0.0f : m;
        }
        {
            float m = -FLT_MAX;
            int w = ews;
            for (; w + 2 <= ewe; w += 2)
                m = fmaxf(fmaxf(m, erow1[w]), erow1[w + 1]);
            if (w < ewe) m = fmaxf(m, erow1[w]);
            vals1[ph] = empty ? 0.0f : m;
        }
    }

    // stage the wave's 784 outputs (k = ch*49 + ph*7 + pw) then write
    // coalesced; cm[wv] reuse is safe after the last reduce (wave-sync).
    float* stage = (float*)cm[wv];
    if (eact) {
        #pragma unroll
        for (int ph = 0; ph < PH; ++ph) {
            stage[ech * 49 + ph * 7 + epw] = vals0[ph];
            stage[(8 + ech) * 49 + ph * 7 + epw] = vals1[ph];
        }
    }
    size_t obase = ((size_t)(r << 9) + c0) * 49;
    #pragma unroll
    for (int it = 0; it < 13; ++it) {
        int f = (it << 6) + lane;
        if (f < 784) out[obase + f] = stage[f];
    }
}

extern "C" void kernel_launch(void* const* d_in, const int* in_sizes, int n_in,
                              void* d_out, int out_size, void* d_ws, size_t ws_size,
                              hipStream_t stream) {
    const float* features = (const float*)d_in[0];
    const float* rois     = (const float*)d_in[1];
    float* out = (float*)d_out;
    int* wsbuf = (int*)d_ws;

    int R = in_sizes[1] / 5;   // 2000

    roi_bounds_kernel<<<(R + 255) / 256, 256, 0, stream>>>(rois, wsbuf, R);
    roipool_main<<<R * 8, 256, 0, stream>>>(features, wsbuf, out);
}

// Round 15
// 237.593 us; speedup vs baseline: 1.3223x; 1.3223x over previous
//
#include <hip/hip_runtime.h>
#include <math.h>
#include <float.h>

#define PH 7
#define RLEN 32   // ints per roi in workspace

// ---- exact integer emulation of the reference's fast-math f32 binning ----
// bin = RN_f32(roi * RN_f32(1/7));  RN_f32(1/7) = 9586981 * 2^-26
#define C7 9586981LL

__device__ __forceinline__ long long round24(long long v) {
    if (v == 0) return 0;
    int L = 64 - __clzll((unsigned long long)v);
    int sh = L - 24;
    if (sh <= 0) return v;
    long long rem  = v & ((1LL << sh) - 1);
    long long base = v >> sh;
    long long half = 1LL << (sh - 1);
    if (rem > half || (rem == half && (base & 1))) base++;
    return base << sh;
}
__device__ __forceinline__ long long bin_q26(int roi) {
    return round24((long long)roi * C7);
}
__device__ __forceinline__ int floor_k(long long b26, int k) {
    long long v = round24((long long)k * b26);
    return (int)(v >> 26);
}
__device__ __forceinline__ int ceil_k(long long b26, int k) {
    long long v = round24((long long)k * b26);
    return (int)((v + ((1LL << 26) - 1)) >> 26);
}

// Per-ROI bounds (ints): [0]=b, [1..7]=hstart, [8..14]=hend,
// [15] = qs | qe<<8 (window column-quad range), [16..22]=ws, [23..29]=we
__global__ void roi_bounds_kernel(const float* __restrict__ rois,
                                  int* __restrict__ wsbuf, int R) {
    int r = blockIdx.x * blockDim.x + threadIdx.x;
    if (r >= R) return;
    const int H = 64, W = 64;
    const float* roi = rois + r * 5;
    int b  = (int)roi[0];
    int x1 = (int)rintf(roi[1] * 0.0625f);
    int y1 = (int)rintf(roi[2] * 0.0625f);
    int x2 = (int)rintf(roi[3] * 0.0625f);
    int y2 = (int)rintf(roi[4] * 0.0625f);

    int roi_w = max(x2 - x1 + 1, 1);
    int roi_h = max(y2 - y1 + 1, 1);
    long long bh = bin_q26(roi_h);
    long long bw = bin_q26(roi_w);

    int* o = wsbuf + r * RLEN;
    o[0] = b;
    int ws0 = 64, we6 = 0;
    #pragma unroll
    for (int i = 0; i < PH; ++i) {
        int hs = min(max(y1 + floor_k(bh, i),     0), H);
        int he = min(max(y1 + ceil_k (bh, i + 1), 0), H);
        int wst = min(max(x1 + floor_k(bw, i),     0), W);
        int wen = min(max(x1 + ceil_k (bw, i + 1), 0), W);
        o[1 + i]  = hs;
        o[8 + i]  = he;
        o[16 + i] = wst;
        o[23 + i] = wen;
        if (i == 0) ws0 = wst;
        if (i == 6) we6 = wen;
    }
    int qs = ws0 >> 2;
    int qe = (we6 + 3) >> 2;
    o[15] = qs | (max(qe, qs) << 8);
}

__device__ __forceinline__ float4 max4(float4 a, float4 b) {
    float4 r;
    r.x = fmaxf(a.x, b.x); r.y = fmaxf(a.y, b.y);
    r.z = fmaxf(a.z, b.z); r.w = fmaxf(a.w, b.w);
    return r;
}

// One wave = 8 channels of one roi. lane = chsub*8 + cq8; quad = qs+tile*8+cq8.
// Per-phase reduce via masked VECTOR LDS reads (bin spans <=4 quads);
// results buffered in registers; one coalesced 392-float write at the end.
// Block = 256 threads = 4 independent waves (no barriers). Grid = R * 16.
__global__ __launch_bounds__(256) void roipool_main(
        const float* __restrict__ features,
        const int* __restrict__ wsbuf,
        float* __restrict__ out) {
    __shared__ float cm[4][8][68];   // [wave][chsub][cols] = 8704 B

    int r    = blockIdx.x >> 4;      // 16 blocks per roi (32 ch each)
    int cg   = blockIdx.x & 15;
    int wv   = threadIdx.x >> 6;
    int lane = threadIdx.x & 63;
    int chsub = lane >> 3;           // 0..7: channel within wave
    int cq8   = lane & 7;            // quad slot within tile
    int c0   = (cg << 5) + (wv << 3);

    const int* B = wsbuf + r * RLEN; // wave-uniform -> scalar loads
    int b   = B[0];
    int qpk = B[15];
    int qs  = qpk & 255;
    int qe  = qpk >> 8;
    int ntiles = (qe - qs + 7) >> 3; // 0..2

    const float4* f4 = (const float4*)features;
    int cbase = ((b << 9) + c0 + chsub) << 10;

    // epilogue lane mapping (8 ch * 7 pw = 56 active lanes)
    int ech = (lane * 9363) >> 16;   // lane/7 for lane<56
    int epw = lane - ech * 7;
    int ews = B[16 + epw];           // per-lane, L1-hot
    int ewe = B[23 + epw];
    bool eact = lane < 56;
    const float* erow = cm[wv][ech & 7];
    int qlo = ews >> 2;
    int qhi = (ewe - 1) >> 2;        // < qlo when bin empty (skip loop)
    float vals[PH];

    #pragma unroll
    for (int ph = 0; ph < PH; ++ph) {
        int hs = B[1 + ph], he = B[8 + ph];   // wave-uniform scalars
        for (int t = 0; t < ntiles; ++t) {
            int qabs = qs + (t << 3) + cq8;
            if (qabs < qe) {
                float4 acc = make_float4(-FLT_MAX, -FLT_MAX, -FLT_MAX, -FLT_MAX);
                int n = he - hs;
                int idx = cbase + (hs << 4) + qabs;
                while (n >= 4) {                  // 4 loads in flight
                    float4 v0 = f4[idx];
                    float4 v1 = f4[idx + 16];
                    float4 v2 = f4[idx + 32];
                    float4 v3 = f4[idx + 48];
                    acc = max4(acc, max4(max4(v0, v1), max4(v2, v3)));
                    idx += 64; n -= 4;
                }
                if (n >= 2) {
                    float4 v0 = f4[idx];
                    float4 v1 = f4[idx + 16];
                    acc = max4(acc, max4(v0, v1));
                    idx += 32; n -= 2;
                }
                if (n > 0) acc = max4(acc, f4[idx]);
                *(float4*)&cm[wv][chsub][qabs << 2] = acc;
            }
        }
        // per-phase reduce: <=4 independent ds_read_b128 + component masks.
        // wave-lockstep program order makes LDS write->read safe (no barrier).
        float m = -FLT_MAX;
        for (int q = qlo; q <= qhi; ++q) {
            float4 v = *(const float4*)&erow[q << 2];
            int c = q << 2;
            m = fmaxf(m, (c     >= ews && c     < ewe) ? v.x : -FLT_MAX);
            m = fmaxf(m, (c + 1 >= ews && c + 1 < ewe) ? v.y : -FLT_MAX);
            m = fmaxf(m, (c + 2 >= ews && c + 2 < ewe) ? v.z : -FLT_MAX);
            m = fmaxf(m, (c + 3 >= ews && c + 3 < ewe) ? v.w : -FLT_MAX);
        }
        bool empty = (he <= hs) || (ewe <= ews);
        vals[ph] = empty ? 0.0f : m;
    }

    // stage the wave's 392 outputs (k = ech*49 + ph*7 + epw) then write
    // coalesced; cm[wv] reuse is safe after the last reduce (wave-sync).
    float* stage = (float*)cm[wv];
    if (eact) {
        #pragma unroll
        for (int ph = 0; ph < PH; ++ph)
            stage[ech * 49 + ph * 7 + epw] = vals[ph];
    }
    size_t obase = ((size_t)(r << 9) + c0) * 49;
    #pragma unroll
    for (int it = 0; it < 7; ++it) {
        int f = (it << 6) + lane;
        if (f < 392) out[obase + f] = stage[f];
    }
}

extern "C" void kernel_launch(void* const* d_in, const int* in_sizes, int n_in,
                              void* d_out, int out_size, void* d_ws, size_t ws_size,
                              hipStream_t stream) {
    const float* features = (const float*)d_in[0];
    const float* rois     = (const float*)d_in[1];
    float* out = (float*)d_out;
    int* wsbuf = (int*)d_ws;

    int R = in_sizes[1] / 5;   // 2000

    roi_bounds_kernel<<<(R + 255) / 256, 256, 0, stream>>>(rois, wsbuf, R);
    roipool_main<<<R * 16, 256, 0, stream>>>(features, wsbuf, out);
}

// Round 16
// 201.486 us; speedup vs baseline: 1.5593x; 1.1792x over previous
//
#include <hip/hip_runtime.h>
#include <math.h>
#include <float.h>

#define PH 7
#define RLEN 32   // ints per roi in workspace

// ---- exact integer emulation of the reference's fast-math f32 binning ----
// bin = RN_f32(roi * RN_f32(1/7));  RN_f32(1/7) = 9586981 * 2^-26
#define C7 9586981LL

__device__ __forceinline__ long long round24(long long v) {
    if (v == 0) return 0;
    int L = 64 - __clzll((unsigned long long)v);
    int sh = L - 24;
    if (sh <= 0) return v;
    long long rem  = v & ((1LL << sh) - 1);
    long long base = v >> sh;
    long long half = 1LL << (sh - 1);
    if (rem > half || (rem == half && (base & 1))) base++;
    return base << sh;
}
__device__ __forceinline__ long long bin_q26(int roi) {
    return round24((long long)roi * C7);
}
__device__ __forceinline__ int floor_k(long long b26, int k) {
    long long v = round24((long long)k * b26);
    return (int)(v >> 26);
}
__device__ __forceinline__ int ceil_k(long long b26, int k) {
    long long v = round24((long long)k * b26);
    return (int)((v + ((1LL << 26) - 1)) >> 26);
}

// Per-ROI bounds (ints): [0]=b, [1..7]=hstart, [8..14]=hend,
// [15] = qs | qe<<8 (window column-quad range), [16..22]=ws, [23..29]=we
__global__ void roi_bounds_kernel(const float* __restrict__ rois,
                                  int* __restrict__ wsbuf, int R) {
    int r = blockIdx.x * blockDim.x + threadIdx.x;
    if (r >= R) return;
    const int H = 64, W = 64;
    const float* roi = rois + r * 5;
    int b  = (int)roi[0];
    int x1 = (int)rintf(roi[1] * 0.0625f);
    int y1 = (int)rintf(roi[2] * 0.0625f);
    int x2 = (int)rintf(roi[3] * 0.0625f);
    int y2 = (int)rintf(roi[4] * 0.0625f);

    int roi_w = max(x2 - x1 + 1, 1);
    int roi_h = max(y2 - y1 + 1, 1);
    long long bh = bin_q26(roi_h);
    long long bw = bin_q26(roi_w);

    int* o = wsbuf + r * RLEN;
    o[0] = b;
    int ws0 = 64, we6 = 0;
    #pragma unroll
    for (int i = 0; i < PH; ++i) {
        int hs = min(max(y1 + floor_k(bh, i),     0), H);
        int he = min(max(y1 + ceil_k (bh, i + 1), 0), H);
        int wst = min(max(x1 + floor_k(bw, i),     0), W);
        int wen = min(max(x1 + ceil_k (bw, i + 1), 0), W);
        o[1 + i]  = hs;
        o[8 + i]  = he;
        o[16 + i] = wst;
        o[23 + i] = wen;
        if (i == 0) ws0 = wst;
        if (i == 6) we6 = wen;
    }
    int qs = ws0 >> 2;
    int qe = (we6 + 3) >> 2;
    o[15] = qs | (max(qe, qs) << 8);
}

__device__ __forceinline__ float4 max4(float4 a, float4 b) {
    float4 r;
    r.x = fmaxf(a.x, b.x); r.y = fmaxf(a.y, b.y);
    r.z = fmaxf(a.z, b.z); r.w = fmaxf(a.w, b.w);
    return r;
}

// One wave = 8 channels of one roi. lane = chsub*8 + cq8.
// Final-row carry across phases (boundary row loaded once) + dual-tile
// single-pass for windows >8 quads (both tiles per row, 4 loads in flight).
// Per-phase scalar reduce into registers; one coalesced 392-float write.
// Block = 256 threads = 4 independent waves (no barriers). Grid = R * 16.
__global__ __launch_bounds__(256) void roipool_main(
        const float* __restrict__ features,
        const int* __restrict__ wsbuf,
        float* __restrict__ out) {
    __shared__ float cm[4][8][68];   // [wave][chsub][cols] = 8704 B

    int r    = blockIdx.x >> 4;      // 16 blocks per roi (32 ch each)
    int cg   = blockIdx.x & 15;
    int wv   = threadIdx.x >> 6;
    int lane = threadIdx.x & 63;
    int chsub = lane >> 3;           // 0..7: channel within wave
    int cq8   = lane & 7;            // quad slot within tile
    int c0   = (cg << 5) + (wv << 3);

    const int* B = wsbuf + r * RLEN; // wave-uniform -> scalar loads
    int b   = B[0];
    int qpk = B[15];
    int qs  = qpk & 255;
    int qe  = qpk >> 8;
    bool dual = (qe - qs) > 8;

    const float4* f4 = (const float4*)features;
    int cbase = ((b << 9) + c0 + chsub) << 10;
    int qabs0 = qs + cq8;
    int qabs1 = qs + 8 + cq8;
    bool m0 = qabs0 < qe;
    bool m1 = qabs1 < qe;
    int qc0 = min(qabs0, 15);        // clamped: loads stay in-bounds for idle lanes
    int qc1 = min(qabs1, 15);

    // epilogue lane mapping (8 ch * 7 pw = 56 active lanes)
    int ech = (lane * 9363) >> 16;   // lane/7 for lane<56
    int epw = lane - ech * 7;
    int ews = B[16 + epw];           // per-lane, L1-hot
    int ewe = B[23 + epw];
    bool eact = lane < 56;
    const float* erow = cm[wv][ech & 7];
    float vals[PH];

    const float4 NEG4 = make_float4(-FLT_MAX, -FLT_MAX, -FLT_MAX, -FLT_MAX);
    float4 last0 = NEG4, last1 = NEG4;   // final-row carry
    int last_h = -100;

    if (!dual) {
        #pragma unroll
        for (int ph = 0; ph < PH; ++ph) {
            int hs = B[1 + ph], he = B[8 + ph];   // wave-uniform scalars
            if (he > hs) {
                bool reuse = (hs == last_h);
                float4 a0 = reuse ? last0 : NEG4;
                int h0 = hs + (reuse ? 1 : 0);
                int nbody = he - h0 - 1;          // rows before the final row
                int idx = cbase + (h0 << 4) + qc0;
                while (nbody >= 4) {              // 4 loads in flight
                    float4 v0 = f4[idx];
                    float4 v1 = f4[idx + 16];
                    float4 v2 = f4[idx + 32];
                    float4 v3 = f4[idx + 48];
                    a0 = max4(a0, max4(max4(v0, v1), max4(v2, v3)));
                    idx += 64; nbody -= 4;
                }
                if (nbody >= 2) {
                    float4 v0 = f4[idx];
                    float4 v1 = f4[idx + 16];
                    a0 = max4(a0, max4(v0, v1));
                    idx += 32; nbody -= 2;
                }
                if (nbody >= 1) a0 = max4(a0, f4[idx]);
                if (he - 1 >= h0) {               // load final row, keep for carry
                    last0 = f4[cbase + ((he - 1) << 4) + qc0];
                    a0 = max4(a0, last0);
                }
                last_h = he - 1;
                if (m0) *(float4*)&cm[wv][chsub][qabs0 << 2] = a0;
            }
            // per-phase reduce; wave-lockstep order makes LDS w->r safe
            float m = -FLT_MAX;
            int w = ews;
            for (; w + 2 <= ewe; w += 2)
                m = fmaxf(fmaxf(m, erow[w]), erow[w + 1]);
            if (w < ewe) m = fmaxf(m, erow[w]);
            bool empty = (he <= hs) || (ewe <= ews);
            vals[ph] = empty ? 0.0f : m;
        }
    } else {
        #pragma unroll
        for (int ph = 0; ph < PH; ++ph) {
            int hs = B[1 + ph], he = B[8 + ph];
            if (he > hs) {
                bool reuse = (hs == last_h);
                float4 a0 = reuse ? last0 : NEG4;
                float4 a1 = reuse ? last1 : NEG4;
                int h0 = hs + (reuse ? 1 : 0);
                int nbody = he - h0 - 1;
                int idx = cbase + (h0 << 4);
                while (nbody >= 2) {              // 4 loads in flight (2 rows x 2 tiles)
                    float4 v00 = f4[idx + qc0];
                    float4 v01 = f4[idx + qc1];
                    float4 v10 = f4[idx + 16 + qc0];
                    float4 v11 = f4[idx + 16 + qc1];
                    a0 = max4(a0, max4(v00, v10));
                    a1 = max4(a1, max4(v01, v11));
                    idx += 32; nbody -= 2;
                }
                if (nbody >= 1) {
                    a0 = max4(a0, f4[idx + qc0]);
                    a1 = max4(a1, f4[idx + qc1]);
                }
                if (he - 1 >= h0) {
                    int fin = cbase + ((he - 1) << 4);
                    last0 = f4[fin + qc0];
                    last1 = f4[fin + qc1];
                    a0 = max4(a0, last0);
                    a1 = max4(a1, last1);
                }
                last_h = he - 1;
                if (m0) *(float4*)&cm[wv][chsub][qabs0 << 2] = a0;
                if (m1) *(float4*)&cm[wv][chsub][qabs1 << 2] = a1;
            }
            float m = -FLT_MAX;
            int w = ews;
            for (; w + 2 <= ewe; w += 2)
                m = fmaxf(fmaxf(m, erow[w]), erow[w + 1]);
            if (w < ewe) m = fmaxf(m, erow[w]);
            bool empty = (he <= hs) || (ewe <= ews);
            vals[ph] = empty ? 0.0f : m;
        }
    }

    // stage the wave's 392 outputs (k = ech*49 + ph*7 + epw) then write
    // coalesced; cm[wv] reuse is safe after the last reduce (wave-sync).
    float* stage = (float*)cm[wv];
    if (eact) {
        #pragma unroll
        for (int ph = 0; ph < PH; ++ph)
            stage[ech * 49 + ph * 7 + epw] = vals[ph];
    }
    size_t obase = ((size_t)(r << 9) + c0) * 49;
    #pragma unroll
    for (int it = 0; it < 7; ++it) {
        int f = (it << 6) + lane;
        if (f < 392) out[obase + f] = stage[f];
    }
}

extern "C" void kernel_launch(void* const* d_in, const int* in_sizes, int n_in,
                              void* d_out, int out_size, void* d_ws, size_t ws_size,
                              hipStream_t stream) {
    const float* features = (const float*)d_in[0];
    const float* rois     = (const float*)d_in[1];
    float* out = (float*)d_out;
    int* wsbuf = (int*)d_ws;

    int R = in_sizes[1] / 5;   // 2000

    roi_bounds_kernel<<<(R + 255) / 256, 256, 0, stream>>>(rois, wsbuf, R);
    roipool_main<<<R * 16, 256, 0, stream>>>(features, wsbuf, out);
}

// Round 17
// 193.175 us; speedup vs baseline: 1.6264x; 1.0430x over previous
//
#include <hip/hip_runtime.h>
#include <math.h>
#include <float.h>

#define PH 7
#define RLEN 32   // ints per roi in workspace

// ---- exact integer emulation of the reference's fast-math f32 binning ----
// bin = RN_f32(roi * RN_f32(1/7));  RN_f32(1/7) = 9586981 * 2^-26
#define C7 9586981LL

__device__ __forceinline__ long long round24(long long v) {
    if (v == 0) return 0;
    int L = 64 - __clzll((unsigned long long)v);
    int sh = L - 24;
    if (sh <= 0) return v;
    long long rem  = v & ((1LL << sh) - 1);
    long long base = v >> sh;
    long long half = 1LL << (sh - 1);
    if (rem > half || (rem == half && (base & 1))) base++;
    return base << sh;
}
__device__ __forceinline__ long long bin_q26(int roi) {
    return round24((long long)roi * C7);
}
__device__ __forceinline__ int floor_k(long long b26, int k) {
    long long v = round24((long long)k * b26);
    return (int)(v >> 26);
}
__device__ __forceinline__ int ceil_k(long long b26, int k) {
    long long v = round24((long long)k * b26);
    return (int)((v + ((1LL << 26) - 1)) >> 26);
}

// Per-ROI bounds (ints): [0]=b, [1..7]=hstart, [8..14]=hend,
// [15] = qs | qe<<8 (window column-quad range), [16..22]=ws, [23..29]=we
__global__ void roi_bounds_kernel(const float* __restrict__ rois,
                                  int* __restrict__ wsbuf, int R) {
    int r = blockIdx.x * blockDim.x + threadIdx.x;
    if (r >= R) return;
    const int H = 64, W = 64;
    const float* roi = rois + r * 5;
    int b  = (int)roi[0];
    int x1 = (int)rintf(roi[1] * 0.0625f);
    int y1 = (int)rintf(roi[2] * 0.0625f);
    int x2 = (int)rintf(roi[3] * 0.0625f);
    int y2 = (int)rintf(roi[4] * 0.0625f);

    int roi_w = max(x2 - x1 + 1, 1);
    int roi_h = max(y2 - y1 + 1, 1);
    long long bh = bin_q26(roi_h);
    long long bw = bin_q26(roi_w);

    int* o = wsbuf + r * RLEN;
    o[0] = b;
    int ws0 = 64, we6 = 0;
    #pragma unroll
    for (int i = 0; i < PH; ++i) {
        int hs = min(max(y1 + floor_k(bh, i),     0), H);
        int he = min(max(y1 + ceil_k (bh, i + 1), 0), H);
        int wst = min(max(x1 + floor_k(bw, i),     0), W);
        int wen = min(max(x1 + ceil_k (bw, i + 1), 0), W);
        o[1 + i]  = hs;
        o[8 + i]  = he;
        o[16 + i] = wst;
        o[23 + i] = wen;
        if (i == 0) ws0 = wst;
        if (i == 6) we6 = wen;
    }
    int qs = ws0 >> 2;
    int qe = (we6 + 3) >> 2;
    o[15] = qs | (max(qe, qs) << 8);
}

__device__ __forceinline__ float4 max4(float4 a, float4 b) {
    float4 r;
    r.x = fmaxf(a.x, b.x); r.y = fmaxf(a.y, b.y);
    r.z = fmaxf(a.z, b.z); r.w = fmaxf(a.w, b.w);
    return r;
}

// One wave = 8 channels of one roi. lane = chsub*8 + cq8.
// Final-row carry + dual-tile single pass (R16) + DOUBLE-BUFFERED cm with a
// one-phase-lagged reduce: reduce[p-1] reads the buffer phase p isn't
// writing, so the compiler can overlap phase p's load latency with it.
// Block = 256 threads = 4 independent waves (no barriers). Grid = R * 16.
__global__ __launch_bounds__(256) void roipool_main(
        const float* __restrict__ features,
        const int* __restrict__ wsbuf,
        float* __restrict__ out) {
    __shared__ float cmA[4][8][68];   // 8704 B
    __shared__ float cmB[4][8][68];   // 8704 B  (total 17.4 KB, still 8 blk/CU)

    int r    = blockIdx.x >> 4;      // 16 blocks per roi (32 ch each)
    int cg   = blockIdx.x & 15;
    int wv   = threadIdx.x >> 6;
    int lane = threadIdx.x & 63;
    int chsub = lane >> 3;           // 0..7: channel within wave
    int cq8   = lane & 7;            // quad slot within tile
    int c0   = (cg << 5) + (wv << 3);

    const int* B = wsbuf + r * RLEN; // wave-uniform -> scalar loads
    int b   = B[0];
    int qpk = B[15];
    int qs  = qpk & 255;
    int qe  = qpk >> 8;
    bool dual = (qe - qs) > 8;

    const float4* f4 = (const float4*)features;
    int cbase = ((b << 9) + c0 + chsub) << 10;
    int qabs0 = qs + cq8;
    int qabs1 = qs + 8 + cq8;
    bool m0 = qabs0 < qe;
    bool m1 = qabs1 < qe;
    int qc1 = min(qabs1, 15);        // clamped (dual tile1 only)

    // epilogue lane mapping (8 ch * 7 pw = 56 active lanes)
    int ech = (lane * 9363) >> 16;   // lane/7 for lane<56
    int epw = lane - ech * 7;
    int ews = B[16 + epw];           // per-lane, L1-hot
    int ewe = B[23 + epw];
    bool eact = lane < 56;
    const float* erowA = cmA[wv][ech & 7];
    const float* erowB = cmB[wv][ech & 7];
    float vals[PH];
    int phs = 0, phe = 0;            // previous phase h-bounds (for lag)

    const float4 NEG4 = make_float4(-FLT_MAX, -FLT_MAX, -FLT_MAX, -FLT_MAX);
    float4 last0 = NEG4, last1 = NEG4;   // final-row carry
    int last_h = -100;

    if (!dual) {
        #pragma unroll
        for (int ph = 0; ph < PH; ++ph) {
            int hs = B[1 + ph], he = B[8 + ph];   // wave-uniform scalars
            float (*cw)[68] = (ph & 1) ? cmB[wv] : cmA[wv];
            if (m0 && he > hs) {                  // masked: idle lanes skip loads
                bool reuse = (hs == last_h);
                float4 a0 = reuse ? last0 : NEG4;
                int h0 = hs + (reuse ? 1 : 0);
                int nbody = he - h0 - 1;          // rows before the final row
                int idx = cbase + (h0 << 4) + qabs0;
                while (nbody >= 4) {              // 4 loads in flight
                    float4 v0 = f4[idx];
                    float4 v1 = f4[idx + 16];
                    float4 v2 = f4[idx + 32];
                    float4 v3 = f4[idx + 48];
                    a0 = max4(a0, max4(max4(v0, v1), max4(v2, v3)));
                    idx += 64; nbody -= 4;
                }
                if (nbody >= 2) {
                    float4 v0 = f4[idx];
                    float4 v1 = f4[idx + 16];
                    a0 = max4(a0, max4(v0, v1));
                    idx += 32; nbody -= 2;
                }
                if (nbody >= 1) a0 = max4(a0, f4[idx]);
                if (he - 1 >= h0) {               // final row: load once, carry
                    last0 = f4[cbase + ((he - 1) << 4) + qabs0];
                    a0 = max4(a0, last0);
                }
                last_h = he - 1;
                *(float4*)&cw[chsub][qabs0 << 2] = a0;
            }
            if (ph > 0) {                         // lagged reduce of ph-1
                const float* er = (ph & 1) ? erowA : erowB;
                float m = -FLT_MAX;
                int w = ews;
                for (; w + 2 <= ewe; w += 2)
                    m = fmaxf(fmaxf(m, er[w]), er[w + 1]);
                if (w < ewe) m = fmaxf(m, er[w]);
                vals[ph - 1] = ((phe <= phs) || (ewe <= ews)) ? 0.0f : m;
            }
            phs = hs; phe = he;
        }
    } else {
        #pragma unroll
        for (int ph = 0; ph < PH; ++ph) {
            int hs = B[1 + ph], he = B[8 + ph];
            float (*cw)[68] = (ph & 1) ? cmB[wv] : cmA[wv];
            if (he > hs) {                        // tile0 fully active in dual
                bool reuse = (hs == last_h);
                float4 a0 = reuse ? last0 : NEG4;
                float4 a1 = reuse ? last1 : NEG4;
                int h0 = hs + (reuse ? 1 : 0);
                int nbody = he - h0 - 1;
                int idx = cbase + (h0 << 4);
                while (nbody >= 2) {              // 4 loads in flight (2 rows x 2 tiles)
                    float4 v00 = f4[idx + qabs0];
                    float4 v01 = f4[idx + qc1];
                    float4 v10 = f4[idx + 16 + qabs0];
                    float4 v11 = f4[idx + 16 + qc1];
                    a0 = max4(a0, max4(v00, v10));
                    a1 = max4(a1, max4(v01, v11));
                    idx += 32; nbody -= 2;
                }
                if (nbody >= 1) {
                    a0 = max4(a0, f4[idx + qabs0]);
                    a1 = max4(a1, f4[idx + qc1]);
                }
                if (he - 1 >= h0) {
                    int fin = cbase + ((he - 1) << 4);
                    last0 = f4[fin + qabs0];
                    last1 = f4[fin + qc1];
                    a0 = max4(a0, last0);
                    a1 = max4(a1, last1);
                }
                last_h = he - 1;
                *(float4*)&cw[chsub][qabs0 << 2] = a0;
                if (m1) *(float4*)&cw[chsub][qabs1 << 2] = a1;
            }
            if (ph > 0) {                         // lagged reduce of ph-1
                const float* er = (ph & 1) ? erowA : erowB;
                float m = -FLT_MAX;
                int w = ews;
                for (; w + 2 <= ewe; w += 2)
                    m = fmaxf(fmaxf(m, er[w]), er[w + 1]);
                if (w < ewe) m = fmaxf(m, er[w]);
                vals[ph - 1] = ((phe <= phs) || (ewe <= ews)) ? 0.0f : m;
            }
            phs = hs; phe = he;
        }
    }
    {   // tail: reduce phase 6 (buffer 6&1 = 0 -> cmA)
        float m = -FLT_MAX;
        int w = ews;
        for (; w + 2 <= ewe; w += 2)
            m = fmaxf(fmaxf(m, erowA[w]), erowA[w + 1]);
        if (w < ewe) m = fmaxf(m, erowA[w]);
        vals[PH - 1] = ((phe <= phs) || (ewe <= ews)) ? 0.0f : m;
    }

    // stage the wave's 392 outputs (k = ech*49 + ph*7 + epw) then write
    // coalesced; cmA reuse is safe after the final reduce (wave-sync).
    float* stage = (float*)cmA[wv];
    if (eact) {
        #pragma unroll
        for (int ph = 0; ph < PH; ++ph)
            stage[ech * 49 + ph * 7 + epw] = vals[ph];
    }
    size_t obase = ((size_t)(r << 9) + c0) * 49;
    #pragma unroll
    for (int it = 0; it < 7; ++it) {
        int f = (it << 6) + lane;
        if (f < 392) out[obase + f] = stage[f];
    }
}

extern "C" void kernel_launch(void* const* d_in, const int* in_sizes, int n_in,
                              void* d_out, int out_size, void* d_ws, size_t ws_size,
                              hipStream_t stream) {
    const float* features = (const float*)d_in[0];
    const float* rois     = (const float*)d_in[1];
    float* out = (float*)d_out;
    int* wsbuf = (int*)d_ws;

    int R = in_sizes[1] / 5;   // 2000

    roi_bounds_kernel<<<(R + 255) / 256, 256, 0, stream>>>(rois, wsbuf, R);
    roipool_main<<<R * 16, 256, 0, stream>>>(features, wsbuf, out);
}